// Round 1
// baseline (231.189 us; speedup 1.0000x reference)
//
#include <hip/hip_runtime.h>

// MPS amplitude: B=8192 elements, L=64 sites, D=32 bond dim, LOCAL=2 spins.
// Block = 256 threads = 32 elements x 8 j-groups (4 output columns each).
// v (current 1x32 complex vector per element) lives in LDS, ping-pong buffered.
// A-matrices are read spin-selected straight from global (L1/L2-resident).

__global__ __launch_bounds__(256, 1) void mps_amp_kernel(
    const int*   __restrict__ spin,
    const float* __restrict__ left_r,  const float* __restrict__ left_i,
    const float* __restrict__ bulk_r,  const float* __restrict__ bulk_i,
    const float* __restrict__ right_r, const float* __restrict__ right_i,
    float2*      __restrict__ out)
{
    __shared__ float2 vbuf[2][32][33];   // [pingpong][element][i], +1 pair pad
    __shared__ float2 red[32][8];

    const int tid = threadIdx.x;
    const int e   = tid & 31;        // element within block
    const int g   = tid >> 5;        // j-group 0..7
    const int j0  = g * 4;           // this thread's 4 output columns
    const int eg  = blockIdx.x * 32 + e;

    // ---- pack this element's 64 spins into two 32-bit masks ----
    unsigned m0 = 0u, m1 = 0u;
    {
        const int4* sp = (const int4*)(spin + (size_t)eg * 64);
        #pragma unroll
        for (int k = 0; k < 8; ++k) {
            int4 q = sp[k];
            m0 |= (unsigned)(q.x & 1) << (4*k + 0);
            m0 |= (unsigned)(q.y & 1) << (4*k + 1);
            m0 |= (unsigned)(q.z & 1) << (4*k + 2);
            m0 |= (unsigned)(q.w & 1) << (4*k + 3);
        }
        #pragma unroll
        for (int k = 0; k < 8; ++k) {
            int4 q = sp[8 + k];
            m1 |= (unsigned)(q.x & 1) << (4*k + 0);
            m1 |= (unsigned)(q.y & 1) << (4*k + 1);
            m1 |= (unsigned)(q.z & 1) << (4*k + 2);
            m1 |= (unsigned)(q.w & 1) << (4*k + 3);
        }
    }

    // ---- init v = left[s0] ----
    {
        const int s0 = (int)(m0 & 1u);
        const float* lr = left_r + s0 * 32;
        const float* li = left_i + s0 * 32;
        #pragma unroll
        for (int d = 0; d < 4; ++d) {
            int i = j0 + d;                       // g-groups cover i = 0..31
            vbuf[0][e][i] = make_float2(lr[i], li[i]);
        }
    }
    __syncthreads();

    // ---- chain over 62 bulk sites ----
    int cur = 0;
    for (int t = 0; t < 62; ++t) {
        const int bit = t + 1;                    // spin column for bulk site t
        const unsigned mw = (bit < 32) ? (m0 >> bit) : (m1 >> (bit - 32));
        const int s = (int)(mw & 1u);

        const float* __restrict__ Ar = bulk_r + (((size_t)(t * 2 + s)) << 10) + j0;
        const float* __restrict__ Ai = bulk_i + (((size_t)(t * 2 + s)) << 10) + j0;

        float wr0=0.f, wi0=0.f, wr1=0.f, wi1=0.f;
        float wr2=0.f, wi2=0.f, wr3=0.f, wi3=0.f;

        #pragma unroll
        for (int i = 0; i < 32; ++i) {
            const float2 vv = vbuf[cur][e][i];
            const float4 r4 = *(const float4*)(Ar + i * 32);
            const float4 q4 = *(const float4*)(Ai + i * 32);
            wr0 = fmaf(vv.x, r4.x, wr0); wr0 = fmaf(-vv.y, q4.x, wr0);
            wi0 = fmaf(vv.x, q4.x, wi0); wi0 = fmaf( vv.y, r4.x, wi0);
            wr1 = fmaf(vv.x, r4.y, wr1); wr1 = fmaf(-vv.y, q4.y, wr1);
            wi1 = fmaf(vv.x, q4.y, wi1); wi1 = fmaf( vv.y, r4.y, wi1);
            wr2 = fmaf(vv.x, r4.z, wr2); wr2 = fmaf(-vv.y, q4.z, wr2);
            wi2 = fmaf(vv.x, q4.z, wi2); wi2 = fmaf( vv.y, r4.z, wi2);
            wr3 = fmaf(vv.x, r4.w, wr3); wr3 = fmaf(-vv.y, q4.w, wr3);
            wi3 = fmaf(vv.x, q4.w, wi3); wi3 = fmaf( vv.y, r4.w, wi3);
        }

        const int nxt = cur ^ 1;
        vbuf[nxt][e][j0 + 0] = make_float2(wr0, wi0);
        vbuf[nxt][e][j0 + 1] = make_float2(wr1, wi1);
        vbuf[nxt][e][j0 + 2] = make_float2(wr2, wi2);
        vbuf[nxt][e][j0 + 3] = make_float2(wr3, wi3);
        __syncthreads();
        cur = nxt;
    }

    // ---- right contraction: amp = sum_j v_j * R[sR][j] ----
    {
        const int sR = (int)((m1 >> 31) & 1u);
        const float* Rr = right_r + sR * 32;
        const float* Ri = right_i + sR * 32;
        float pr = 0.f, pi = 0.f;
        #pragma unroll
        for (int d = 0; d < 4; ++d) {
            int j = j0 + d;
            float2 vv = vbuf[cur][e][j];
            float xr = Rr[j], xi = Ri[j];
            pr = fmaf(vv.x, xr, pr); pr = fmaf(-vv.y, xi, pr);
            pi = fmaf(vv.x, xi, pi); pi = fmaf( vv.y, xr, pi);
        }
        red[e][g] = make_float2(pr, pi);
    }
    __syncthreads();

    if (tid < 32) {
        float2 a = red[tid][0];
        #pragma unroll
        for (int k = 1; k < 8; ++k) { a.x += red[tid][k].x; a.y += red[tid][k].y; }
        out[blockIdx.x * 32 + tid] = a;
    }
}

extern "C" void kernel_launch(void* const* d_in, const int* in_sizes, int n_in,
                              void* d_out, int out_size, void* d_ws, size_t ws_size,
                              hipStream_t stream)
{
    const int*   spin = (const int*)  d_in[0];
    const float* lr   = (const float*)d_in[1];
    const float* li   = (const float*)d_in[2];
    const float* br   = (const float*)d_in[3];
    const float* bi   = (const float*)d_in[4];
    const float* rr   = (const float*)d_in[5];
    const float* ri   = (const float*)d_in[6];
    float2* out = (float2*)d_out;

    mps_amp_kernel<<<dim3(256), dim3(256), 0, stream>>>(spin, lr, li, br, bi, rr, ri, out);
}

// Round 2
// 131.917 us; speedup vs baseline: 1.7525x; 1.7525x over previous
//
#include <hip/hip_runtime.h>
#include <stdint.h>

// MPS amplitude: B=8192, L=64 sites, D=32, LOCAL=2.
// Block = 256 threads = 32 elements x 8 j-groups (4 output columns each).
// Per site, BOTH spin matrices (r+i, 16KB) are staged global->LDS with
// global_load_lds (async DMA), double-buffered with counted vmcnt(4) and raw
// s_barriers so staging latency hides under compute. Compute reads A via
// ds_read_b128 (4 distinct addrs/wave -> broadcast). v ping-pongs in LDS.

__device__ __forceinline__ void gl16(const void* g, void* l) {
    __builtin_amdgcn_global_load_lds(
        (const __attribute__((address_space(1))) void*)g,
        (__attribute__((address_space(3))) void*)l,
        16, 0, 0);
}

__global__ __launch_bounds__(256, 1) void mps_amp_kernel(
    const int*   __restrict__ spin,
    const float* __restrict__ left_r,  const float* __restrict__ left_i,
    const float* __restrict__ bulk_r,  const float* __restrict__ bulk_i,
    const float* __restrict__ right_r, const float* __restrict__ right_i,
    float2*      __restrict__ out)
{
    __shared__ float stage_r[2][2048];   // [buf][spin*1024 + i*32 + j]  8KB each
    __shared__ float stage_i[2][2048];
    __shared__ float2 vbuf[2][32][33];   // [pingpong][element][i], +1 pair pad
    __shared__ float2 red[32][8];

    const int tid = threadIdx.x;
    const int e   = tid & 31;        // element within block
    const int g   = tid >> 5;        // j-group 0..7
    const int j0  = g * 4;           // this thread's 4 output columns
    const int eg  = blockIdx.x * 32 + e;

    // ---- pack this element's 64 spins into two 32-bit masks ----
    unsigned m0 = 0u, m1 = 0u;
    {
        const int4* sp = (const int4*)(spin + (size_t)eg * 64);
        #pragma unroll
        for (int k = 0; k < 8; ++k) {
            int4 q = sp[k];
            m0 |= (unsigned)(q.x & 1) << (4*k + 0);
            m0 |= (unsigned)(q.y & 1) << (4*k + 1);
            m0 |= (unsigned)(q.z & 1) << (4*k + 2);
            m0 |= (unsigned)(q.w & 1) << (4*k + 3);
        }
        #pragma unroll
        for (int k = 0; k < 8; ++k) {
            int4 q = sp[8 + k];
            m1 |= (unsigned)(q.x & 1) << (4*k + 0);
            m1 |= (unsigned)(q.y & 1) << (4*k + 1);
            m1 |= (unsigned)(q.z & 1) << (4*k + 2);
            m1 |= (unsigned)(q.w & 1) << (4*k + 3);
        }
    }

    // ---- issue staging for sites 0 and 1 (4 x 16B per thread per site) ----
    {
        const float* sr0 = bulk_r;            // site 0 = bulk_r + 0*2048
        const float* si0 = bulk_i;
        gl16(sr0 + tid*4,        &stage_r[0][0] + tid*4);
        gl16(sr0 + 1024 + tid*4, &stage_r[0][0] + 1024 + tid*4);
        gl16(si0 + tid*4,        &stage_i[0][0] + tid*4);
        gl16(si0 + 1024 + tid*4, &stage_i[0][0] + 1024 + tid*4);
        const float* sr1 = bulk_r + 2048;
        const float* si1 = bulk_i + 2048;
        gl16(sr1 + tid*4,        &stage_r[1][0] + tid*4);
        gl16(sr1 + 1024 + tid*4, &stage_r[1][0] + 1024 + tid*4);
        gl16(si1 + tid*4,        &stage_i[1][0] + tid*4);
        gl16(si1 + 1024 + tid*4, &stage_i[1][0] + 1024 + tid*4);
    }

    // ---- init v = left[s0] ----
    {
        const int s0 = (int)(m0 & 1u);
        const float* lr = left_r + s0 * 32;
        const float* li = left_i + s0 * 32;
        #pragma unroll
        for (int d = 0; d < 4; ++d) {
            int i = j0 + d;                       // g-groups cover i = 0..31
            vbuf[0][e][i] = make_float2(lr[i], li[i]);
        }
    }
    // site-0 staging (first 4 loads) complete; vbuf writes drained; then barrier
    asm volatile("s_waitcnt vmcnt(4) lgkmcnt(0)" ::: "memory");
    __builtin_amdgcn_s_barrier();

    // ---- chain over 62 bulk sites ----
    int cur = 0;
    for (int t = 0; t < 62; ++t) {
        const int p = t & 1;
        const int bit = t + 1;                    // spin column for bulk site t
        const unsigned mw = (bit < 32) ? (m0 >> bit) : (m1 >> (bit - 32));
        const int s = (int)(mw & 1u);

        const float* __restrict__ Ar = &stage_r[p][0] + s * 1024 + j0;
        const float* __restrict__ Ai = &stage_i[p][0] + s * 1024 + j0;

        float wr0=0.f, wi0=0.f, wr1=0.f, wi1=0.f;
        float wr2=0.f, wi2=0.f, wr3=0.f, wi3=0.f;

        #pragma unroll
        for (int i = 0; i < 32; ++i) {
            const float2 vv = vbuf[cur][e][i];
            const float4 r4 = *(const float4*)(Ar + i * 32);
            const float4 q4 = *(const float4*)(Ai + i * 32);
            wr0 = fmaf(vv.x, r4.x, wr0); wr0 = fmaf(-vv.y, q4.x, wr0);
            wi0 = fmaf(vv.x, q4.x, wi0); wi0 = fmaf( vv.y, r4.x, wi0);
            wr1 = fmaf(vv.x, r4.y, wr1); wr1 = fmaf(-vv.y, q4.y, wr1);
            wi1 = fmaf(vv.x, q4.y, wi1); wi1 = fmaf( vv.y, r4.y, wi1);
            wr2 = fmaf(vv.x, r4.z, wr2); wr2 = fmaf(-vv.y, q4.z, wr2);
            wi2 = fmaf(vv.x, q4.z, wi2); wi2 = fmaf( vv.y, r4.z, wi2);
            wr3 = fmaf(vv.x, r4.w, wr3); wr3 = fmaf(-vv.y, q4.w, wr3);
            wi3 = fmaf(vv.x, q4.w, wi3); wi3 = fmaf( vv.y, r4.w, wi3);
        }

        const int nxt = cur ^ 1;
        vbuf[nxt][e][j0 + 0] = make_float2(wr0, wi0);
        vbuf[nxt][e][j0 + 1] = make_float2(wr1, wi1);
        vbuf[nxt][e][j0 + 2] = make_float2(wr2, wi2);
        vbuf[nxt][e][j0 + 3] = make_float2(wr3, wi3);

        // barrier 1: all waves done reading stage[p] and vbuf[cur]
        asm volatile("s_waitcnt lgkmcnt(0)" ::: "memory");
        __builtin_amdgcn_s_barrier();

        // prefetch site t+2 into the buffer we just finished reading
        if (t < 60) {
            const float* sr = bulk_r + (size_t)(t + 2) * 2048;
            const float* si = bulk_i + (size_t)(t + 2) * 2048;
            gl16(sr + tid*4,        &stage_r[p][0] + tid*4);
            gl16(sr + 1024 + tid*4, &stage_r[p][0] + 1024 + tid*4);
            gl16(si + tid*4,        &stage_i[p][0] + tid*4);
            gl16(si + 1024 + tid*4, &stage_i[p][0] + 1024 + tid*4);
            // drain site t+1's 4 loads, leave t+2's 4 in flight
            asm volatile("s_waitcnt vmcnt(4)" ::: "memory");
        } else if (t == 60) {
            // last pending group is site 61's 4 loads
            asm volatile("s_waitcnt vmcnt(0)" ::: "memory");
        }
        // barrier 2: site t+1's staged data visible to all waves
        __builtin_amdgcn_s_barrier();
        cur = nxt;
    }

    // ---- right contraction: amp = sum_j v_j * R[sR][j] ----
    {
        const int sR = (int)((m1 >> 31) & 1u);
        const float* Rr = right_r + sR * 32;
        const float* Ri = right_i + sR * 32;
        float pr = 0.f, pi = 0.f;
        #pragma unroll
        for (int d = 0; d < 4; ++d) {
            int j = j0 + d;
            float2 vv = vbuf[cur][e][j];
            float xr = Rr[j], xi = Ri[j];
            pr = fmaf(vv.x, xr, pr); pr = fmaf(-vv.y, xi, pr);
            pi = fmaf(vv.x, xi, pi); pi = fmaf( vv.y, xr, pi);
        }
        red[e][g] = make_float2(pr, pi);
    }
    __syncthreads();

    if (tid < 32) {
        float2 a = red[tid][0];
        #pragma unroll
        for (int k = 1; k < 8; ++k) { a.x += red[tid][k].x; a.y += red[tid][k].y; }
        out[blockIdx.x * 32 + tid] = a;
    }
}

extern "C" void kernel_launch(void* const* d_in, const int* in_sizes, int n_in,
                              void* d_out, int out_size, void* d_ws, size_t ws_size,
                              hipStream_t stream)
{
    const int*   spin = (const int*)  d_in[0];
    const float* lr   = (const float*)d_in[1];
    const float* li   = (const float*)d_in[2];
    const float* br   = (const float*)d_in[3];
    const float* bi   = (const float*)d_in[4];
    const float* rr   = (const float*)d_in[5];
    const float* ri   = (const float*)d_in[6];
    float2* out = (float2*)d_out;

    mps_amp_kernel<<<dim3(256), dim3(256), 0, stream>>>(spin, lr, li, br, bi, rr, ri, out);
}

// Round 3
// 103.971 us; speedup vs baseline: 2.2236x; 1.2688x over previous
//
#include <hip/hip_runtime.h>
#include <stdint.h>

// MPS amplitude: B=8192, L=64 sites, D=32, LOCAL=2.
// Block = 256 threads = 32 elements x 8 j-groups (4 output columns each).
// Per site, BOTH spin matrices (r+i, 16KB) staged global->LDS via
// global_load_lds, double-buffered, counted vmcnt(4), raw s_barriers.
// Spin-1 matrix padded to float offset 1032 (bank offset 8) so the wave's
// 4 distinct A-addresses hit disjoint bank-quads {0,4,8,12}: conflict-free.
// Inner loop uses <2 x float> fma -> v_pk_fma_f32 (packed fp32, gfx90a+).

typedef float v2f __attribute__((ext_vector_type(2)));

__device__ __forceinline__ void gl16(const void* g, void* l) {
    __builtin_amdgcn_global_load_lds(
        (const __attribute__((address_space(1))) void*)g,
        (__attribute__((address_space(3))) void*)l,
        16, 0, 0);
}

__global__ __launch_bounds__(256, 1) void mps_amp_kernel(
    const int*   __restrict__ spin,
    const float* __restrict__ left_r,  const float* __restrict__ left_i,
    const float* __restrict__ bulk_r,  const float* __restrict__ bulk_i,
    const float* __restrict__ right_r, const float* __restrict__ right_i,
    float2*      __restrict__ out)
{
    __shared__ float stage_r[2][2064];   // [buf][spin*1032 + i*32 + j]
    __shared__ float stage_i[2][2064];
    __shared__ float2 vbuf[2][32][33];   // [pingpong][element][i], +1 pair pad
    __shared__ float2 red[32][8];

    const int tid = threadIdx.x;
    const int e   = tid & 31;        // element within block
    const int g   = tid >> 5;        // j-group 0..7
    const int j0  = g * 4;           // this thread's 4 output columns
    const int eg  = blockIdx.x * 32 + e;

    // ---- pack this element's 64 spins into two 32-bit masks ----
    unsigned m0 = 0u, m1 = 0u;
    {
        const int4* sp = (const int4*)(spin + (size_t)eg * 64);
        #pragma unroll
        for (int k = 0; k < 8; ++k) {
            int4 q = sp[k];
            m0 |= (unsigned)(q.x & 1) << (4*k + 0);
            m0 |= (unsigned)(q.y & 1) << (4*k + 1);
            m0 |= (unsigned)(q.z & 1) << (4*k + 2);
            m0 |= (unsigned)(q.w & 1) << (4*k + 3);
        }
        #pragma unroll
        for (int k = 0; k < 8; ++k) {
            int4 q = sp[8 + k];
            m1 |= (unsigned)(q.x & 1) << (4*k + 0);
            m1 |= (unsigned)(q.y & 1) << (4*k + 1);
            m1 |= (unsigned)(q.z & 1) << (4*k + 2);
            m1 |= (unsigned)(q.w & 1) << (4*k + 3);
        }
    }

    // ---- issue staging for sites 0 and 1 ----
    // Each site: spin0 -> [0..1023], spin1 -> [1032..2055] (bank offset 8).
    {
        const float* sr0 = bulk_r;
        const float* si0 = bulk_i;
        gl16(sr0 + tid*4,        &stage_r[0][0]    + tid*4);
        gl16(sr0 + 1024 + tid*4, &stage_r[0][1032] + tid*4);
        gl16(si0 + tid*4,        &stage_i[0][0]    + tid*4);
        gl16(si0 + 1024 + tid*4, &stage_i[0][1032] + tid*4);
        const float* sr1 = bulk_r + 2048;
        const float* si1 = bulk_i + 2048;
        gl16(sr1 + tid*4,        &stage_r[1][0]    + tid*4);
        gl16(sr1 + 1024 + tid*4, &stage_r[1][1032] + tid*4);
        gl16(si1 + tid*4,        &stage_i[1][0]    + tid*4);
        gl16(si1 + 1024 + tid*4, &stage_i[1][1032] + tid*4);
    }

    // ---- init v = left[s0] ----
    {
        const int s0 = (int)(m0 & 1u);
        const float* lr = left_r + s0 * 32;
        const float* li = left_i + s0 * 32;
        #pragma unroll
        for (int d = 0; d < 4; ++d) {
            int i = j0 + d;                       // g-groups cover i = 0..31
            vbuf[0][e][i] = make_float2(lr[i], li[i]);
        }
    }
    asm volatile("s_waitcnt vmcnt(4) lgkmcnt(0)" ::: "memory");
    __builtin_amdgcn_s_barrier();

    // ---- chain over 62 bulk sites ----
    int cur = 0;
    for (int t = 0; t < 62; ++t) {
        const int p = t & 1;
        const int bit = t + 1;
        const unsigned mw = (bit < 32) ? (m0 >> bit) : (m1 >> (bit - 32));
        const int s = (int)(mw & 1u);

        const float* __restrict__ Ar = &stage_r[p][0] + s * 1032 + j0;
        const float* __restrict__ Ai = &stage_i[p][0] + s * 1032 + j0;

        v2f wr01 = {0.f, 0.f}, wr23 = {0.f, 0.f};
        v2f wi01 = {0.f, 0.f}, wi23 = {0.f, 0.f};

        #pragma unroll
        for (int i = 0; i < 32; ++i) {
            const float2 vv = vbuf[cur][e][i];
            const float4 r4 = *(const float4*)(Ar + i * 32);
            const float4 q4 = *(const float4*)(Ai + i * 32);
            const v2f r01 = {r4.x, r4.y}, r23 = {r4.z, r4.w};
            const v2f q01 = {q4.x, q4.y}, q23 = {q4.z, q4.w};
            const v2f vx  = {vv.x,  vv.x};
            const v2f vy  = {vv.y,  vv.y};
            const v2f nvy = {-vv.y, -vv.y};
            wr01 = __builtin_elementwise_fma(vx,  r01, wr01);
            wr01 = __builtin_elementwise_fma(nvy, q01, wr01);
            wr23 = __builtin_elementwise_fma(vx,  r23, wr23);
            wr23 = __builtin_elementwise_fma(nvy, q23, wr23);
            wi01 = __builtin_elementwise_fma(vx,  q01, wi01);
            wi01 = __builtin_elementwise_fma(vy,  r01, wi01);
            wi23 = __builtin_elementwise_fma(vx,  q23, wi23);
            wi23 = __builtin_elementwise_fma(vy,  r23, wi23);
        }

        const int nxt = cur ^ 1;
        vbuf[nxt][e][j0 + 0] = make_float2(wr01.x, wi01.x);
        vbuf[nxt][e][j0 + 1] = make_float2(wr01.y, wi01.y);
        vbuf[nxt][e][j0 + 2] = make_float2(wr23.x, wi23.x);
        vbuf[nxt][e][j0 + 3] = make_float2(wr23.y, wi23.y);

        // barrier 1: all waves done reading stage[p] and vbuf[cur]
        asm volatile("s_waitcnt lgkmcnt(0)" ::: "memory");
        __builtin_amdgcn_s_barrier();

        // prefetch site t+2 into the buffer just drained
        if (t < 60) {
            const float* sr = bulk_r + (size_t)(t + 2) * 2048;
            const float* si = bulk_i + (size_t)(t + 2) * 2048;
            gl16(sr + tid*4,        &stage_r[p][0]    + tid*4);
            gl16(sr + 1024 + tid*4, &stage_r[p][1032] + tid*4);
            gl16(si + tid*4,        &stage_i[p][0]    + tid*4);
            gl16(si + 1024 + tid*4, &stage_i[p][1032] + tid*4);
            asm volatile("s_waitcnt vmcnt(4)" ::: "memory");
        } else if (t == 60) {
            asm volatile("s_waitcnt vmcnt(0)" ::: "memory");
        }
        // barrier 2: site t+1's staged data visible to all waves
        __builtin_amdgcn_s_barrier();
        cur = nxt;
    }

    // ---- right contraction: amp = sum_j v_j * R[sR][j] ----
    {
        const int sR = (int)((m1 >> 31) & 1u);
        const float* Rr = right_r + sR * 32;
        const float* Ri = right_i + sR * 32;
        float pr = 0.f, pi = 0.f;
        #pragma unroll
        for (int d = 0; d < 4; ++d) {
            int j = j0 + d;
            float2 vv = vbuf[cur][e][j];
            float xr = Rr[j], xi = Ri[j];
            pr = fmaf(vv.x, xr, pr); pr = fmaf(-vv.y, xi, pr);
            pi = fmaf(vv.x, xi, pi); pi = fmaf( vv.y, xr, pi);
        }
        red[e][g] = make_float2(pr, pi);
    }
    __syncthreads();

    if (tid < 32) {
        float2 a = red[tid][0];
        #pragma unroll
        for (int k = 1; k < 8; ++k) { a.x += red[tid][k].x; a.y += red[tid][k].y; }
        out[blockIdx.x * 32 + tid] = a;
    }
}

extern "C" void kernel_launch(void* const* d_in, const int* in_sizes, int n_in,
                              void* d_out, int out_size, void* d_ws, size_t ws_size,
                              hipStream_t stream)
{
    const int*   spin = (const int*)  d_in[0];
    const float* lr   = (const float*)d_in[1];
    const float* li   = (const float*)d_in[2];
    const float* br   = (const float*)d_in[3];
    const float* bi   = (const float*)d_in[4];
    const float* rr   = (const float*)d_in[5];
    const float* ri   = (const float*)d_in[6];
    float2* out = (float2*)d_out;

    mps_amp_kernel<<<dim3(256), dim3(256), 0, stream>>>(spin, lr, li, br, bi, rr, ri, out);
}

// Round 4
// 57.822 us; speedup vs baseline: 3.9983x; 1.7981x over previous
//
#include <hip/hip_runtime.h>
#include <stdint.h>

// MPS amplitude via MFMA: B=8192, L=64 sites, D=32, LOCAL=2.
// Block = 256 threads (4 waves) = 32 elements. Per site t, compute BOTH
// spin products w_s = V @ B_s as bf16-split MFMA GEMMs (M=32,K=64,N=32),
// then cndmask-select per element by its spin bit.
//   B_s rows (K=64): k=2u -> Ar_s[u][:], k=2u+1 -> Ai_s[u][:]  (interleaved)
//   w_r: V_r[e][2u]=vr_u, [2u+1]=-vi_u ; w_i: V_i[2u]=vi_u, [2u+1]=vr_u
// V_r/V_i both derived in-register from base packed (vr,vi) pairs, so ONE
// shared B in LDS. Split-bf16 3 terms: Vh@Bh + Vh@Bl + Vl@Bh (fp32 accum).
// v chain lives in transposed LDS vT[w=2j+p][e] (+pad), ping-pong per site.
// B fragments rebuilt per site by a cooperative convert pass reading bulk
// straight from global (L2-resident, 16KB/site). One __syncthreads per site.

typedef __attribute__((ext_vector_type(4))) float        f32x4;
typedef __attribute__((ext_vector_type(8))) short        s16x8;
typedef __attribute__((ext_vector_type(4))) unsigned int u32x4;

__device__ __forceinline__ unsigned cvt_pk_bf16(float lo, float hi) {
    unsigned r;
    asm("v_cvt_pk_bf16_f32 %0, %1, %2" : "=v"(r) : "v"(lo), "v"(hi));
    return r;
}
__device__ __forceinline__ float lo_f(unsigned h) { return __uint_as_float(h << 16); }
__device__ __forceinline__ float hi_f(unsigned h) { return __uint_as_float(h & 0xFFFF0000u); }
__device__ __forceinline__ s16x8 frg(u32x4 x) { return __builtin_bit_cast(s16x8, x); }

__global__ __launch_bounds__(256, 1) void mps_mfma_kernel(
    const int*   __restrict__ spin,
    const float* __restrict__ left_r,  const float* __restrict__ left_i,
    const float* __restrict__ bulk_r,  const float* __restrict__ bulk_i,
    const float* __restrict__ right_r, const float* __restrict__ right_i,
    float2*      __restrict__ out)
{
    // [buf][hl][s][kk][g][col][ks] : bf16 B fragments, 16KB per buf
    __shared__ unsigned short Bf[2][2][2][2][4][32][8];
    __shared__ float vT[2][64][33];      // [buf][w=2j+p][e], pad 33
    __shared__ float2 red[32][8];
    __shared__ unsigned smask[32][2];

    const int tid  = threadIdx.x;
    const int l    = tid & 63;
    const int wid  = tid >> 6;           // wave 0..3
    const int mt   = wid >> 1;           // M-tile (element half)
    const int nt   = wid & 1;            // N-tile (column half)
    const int lr16 = l & 15;
    const int lg   = l >> 4;             // k-group 0..3
    const int ve   = mt * 16 + lr16;     // A-row element for V frags
    const int jc   = nt * 16 + lr16;     // C column
    const int blk  = blockIdx.x;

    // conversion-duty mapping: col 0..31, combos c0 and c0+8 (s,kk,g)
    const int ccol = tid & 31;
    const int c0   = tid >> 5;

    auto convert = [&](int site, int buf) {
        const float* br = bulk_r + (size_t)site * 2048 + ccol;
        const float* bi = bulk_i + (size_t)site * 2048 + ccol;
        #pragma unroll
        for (int h = 0; h < 2; ++h) {
            const int c  = c0 + h * 8;
            const int s  = c >> 3;
            const int kk = (c >> 2) & 1;
            const int g  = c & 3;
            const int ub = kk * 16 + 2 * g;
            const float* R = br + s * 1024;
            const float* I = bi + s * 1024;
            float v0 = R[(ub + 0) * 32], v1 = I[(ub + 0) * 32];
            float v2 = R[(ub + 1) * 32], v3 = I[(ub + 1) * 32];
            float v4 = R[(ub + 8) * 32], v5 = I[(ub + 8) * 32];
            float v6 = R[(ub + 9) * 32], v7 = I[(ub + 9) * 32];
            unsigned h0 = cvt_pk_bf16(v0, v1), h1 = cvt_pk_bf16(v2, v3);
            unsigned h2 = cvt_pk_bf16(v4, v5), h3 = cvt_pk_bf16(v6, v7);
            unsigned l0 = cvt_pk_bf16(v0 - lo_f(h0), v1 - hi_f(h0));
            unsigned l1 = cvt_pk_bf16(v2 - lo_f(h1), v3 - hi_f(h1));
            unsigned l2 = cvt_pk_bf16(v4 - lo_f(h2), v5 - hi_f(h2));
            unsigned l3 = cvt_pk_bf16(v6 - lo_f(h3), v7 - hi_f(h3));
            *(u32x4*)&Bf[buf][0][s][kk][g][ccol][0] = (u32x4){h0, h1, h2, h3};
            *(u32x4*)&Bf[buf][1][s][kk][g][ccol][0] = (u32x4){l0, l1, l2, l3};
        }
    };

    // ---- prologue: spin masks, left-init of vT[0], convert site 0 ----
    if (tid < 32) {
        const int* sp = spin + ((size_t)(blk * 32 + tid)) * 64;
        unsigned a0 = 0, a1 = 0;
        #pragma unroll
        for (int k = 0; k < 32; ++k) a0 |= (unsigned)(sp[k] & 1) << k;
        #pragma unroll
        for (int k = 0; k < 32; ++k) a1 |= (unsigned)(sp[32 + k] & 1) << k;
        smask[tid][0] = a0; smask[tid][1] = a1;
    }
    {
        const int e = tid & 31, jg = tid >> 5;
        const int s0 = spin[((size_t)(blk * 32 + e)) * 64] & 1;
        #pragma unroll
        for (int d = 0; d < 4; ++d) {
            const int j = jg * 4 + d;
            vT[0][2 * j    ][e] = left_r[s0 * 32 + j];
            vT[0][2 * j + 1][e] = left_i[s0 * 32 + j];
        }
    }
    convert(0, 0);
    __syncthreads();

    // per-lane spin words for its 4 C-row elements
    unsigned em0[4], em1[4];
    #pragma unroll
    for (int r = 0; r < 4; ++r) {
        const int ee = mt * 16 + lg * 4 + r;
        em0[r] = smask[ee][0];
        em1[r] = smask[ee][1];
    }

    // ---- chain over 62 bulk sites, one barrier per site ----
    #pragma unroll 2
    for (int t = 0; t < 62; ++t) {
        const int b = t & 1;

        // V read (strided b32) : f[kk*8+q*4+r] = V[e][k], k = kk*32+q*16+4g+r
        float f[16];
        #pragma unroll
        for (int kk = 0; kk < 2; ++kk)
            #pragma unroll
            for (int q = 0; q < 2; ++q)
                #pragma unroll
                for (int r = 0; r < 4; ++r)
                    f[kk * 8 + q * 4 + r] = vT[b][kk * 32 + q * 16 + 4 * lg + r][ve];

        // split into bf16 hi/lo packed (vr,vi) pairs
        u32x4 Vh[2], Vl[2];
        #pragma unroll
        for (int kk = 0; kk < 2; ++kk)
            #pragma unroll
            for (int q = 0; q < 2; ++q) {
                const float a = f[kk*8+q*4+0], c2 = f[kk*8+q*4+1];
                const float d2 = f[kk*8+q*4+2], e2 = f[kk*8+q*4+3];
                const unsigned h0 = cvt_pk_bf16(a, c2);
                const unsigned h1 = cvt_pk_bf16(d2, e2);
                Vh[kk][q*2+0] = h0;
                Vh[kk][q*2+1] = h1;
                Vl[kk][q*2+0] = cvt_pk_bf16(a - lo_f(h0), c2 - hi_f(h0));
                Vl[kk][q*2+1] = cvt_pk_bf16(d2 - lo_f(h1), e2 - hi_f(h1));
            }

        // B fragments (one b128 each)
        u32x4 Bh[2][2], Bl[2][2];
        #pragma unroll
        for (int s = 0; s < 2; ++s)
            #pragma unroll
            for (int kk = 0; kk < 2; ++kk) {
                Bh[s][kk] = *(const u32x4*)&Bf[b][0][s][kk][lg][jc][0];
                Bl[s][kk] = *(const u32x4*)&Bf[b][1][s][kk][lg][jc][0];
            }

        // issue next site's conversion (global loads overlap MFMA)
        if (t < 61) convert(t + 1, b ^ 1);

        f32x4 ar[2] = {{0,0,0,0},{0,0,0,0}};
        f32x4 ai[2] = {{0,0,0,0},{0,0,0,0}};

        // w_r : V_r = (vr, -vi)  -> flip hi bf16 sign
        #pragma unroll
        for (int kk = 0; kk < 2; ++kk) {
            u32x4 vh, vl;
            #pragma unroll
            for (int q = 0; q < 4; ++q) {
                vh[q] = Vh[kk][q] ^ 0x80000000u;
                vl[q] = Vl[kk][q] ^ 0x80000000u;
            }
            #pragma unroll
            for (int s = 0; s < 2; ++s) {
                ar[s] = __builtin_amdgcn_mfma_f32_16x16x32_bf16(frg(vh), frg(Bh[s][kk]), ar[s], 0, 0, 0);
                ar[s] = __builtin_amdgcn_mfma_f32_16x16x32_bf16(frg(vh), frg(Bl[s][kk]), ar[s], 0, 0, 0);
                ar[s] = __builtin_amdgcn_mfma_f32_16x16x32_bf16(frg(vl), frg(Bh[s][kk]), ar[s], 0, 0, 0);
            }
        }
        // w_i : V_i = (vi, vr) -> swap halves
        #pragma unroll
        for (int kk = 0; kk < 2; ++kk) {
            u32x4 vh, vl;
            #pragma unroll
            for (int q = 0; q < 4; ++q) {
                vh[q] = __builtin_amdgcn_alignbit(Vh[kk][q], Vh[kk][q], 16);
                vl[q] = __builtin_amdgcn_alignbit(Vl[kk][q], Vl[kk][q], 16);
            }
            #pragma unroll
            for (int s = 0; s < 2; ++s) {
                ai[s] = __builtin_amdgcn_mfma_f32_16x16x32_bf16(frg(vh), frg(Bh[s][kk]), ai[s], 0, 0, 0);
                ai[s] = __builtin_amdgcn_mfma_f32_16x16x32_bf16(frg(vh), frg(Bl[s][kk]), ai[s], 0, 0, 0);
                ai[s] = __builtin_amdgcn_mfma_f32_16x16x32_bf16(frg(vl), frg(Bh[s][kk]), ai[s], 0, 0, 0);
            }
        }

        // select by spin bit and write next v (transposed)
        const int bp = t + 1;
        #pragma unroll
        for (int r = 0; r < 4; ++r) {
            const unsigned mw = (bp < 32) ? em0[r] : em1[r];
            const bool sb = (mw >> (bp & 31)) & 1u;
            const int ee = mt * 16 + lg * 4 + r;
            vT[b ^ 1][2 * jc    ][ee] = sb ? ar[1][r] : ar[0][r];
            vT[b ^ 1][2 * jc + 1][ee] = sb ? ai[1][r] : ai[0][r];
        }
        __syncthreads();
    }

    // ---- right contraction ----
    {
        const int e = tid & 31, jg = tid >> 5;
        const unsigned sR = (smask[e][1] >> 31) & 1u;
        const float* Rr = right_r + sR * 32;
        const float* Ri = right_i + sR * 32;
        float pr = 0.f, pi = 0.f;
        #pragma unroll
        for (int d = 0; d < 4; ++d) {
            const int j = jg * 4 + d;
            const float vr = vT[0][2 * j][e], vi = vT[0][2 * j + 1][e];
            pr += vr * Rr[j] - vi * Ri[j];
            pi += vr * Ri[j] + vi * Rr[j];
        }
        red[e][jg] = make_float2(pr, pi);
    }
    __syncthreads();
    if (tid < 32) {
        float2 a = red[tid][0];
        #pragma unroll
        for (int k = 1; k < 8; ++k) { a.x += red[tid][k].x; a.y += red[tid][k].y; }
        out[blk * 32 + tid] = a;
    }
}

extern "C" void kernel_launch(void* const* d_in, const int* in_sizes, int n_in,
                              void* d_out, int out_size, void* d_ws, size_t ws_size,
                              hipStream_t stream)
{
    const int*   spin = (const int*)  d_in[0];
    const float* lr   = (const float*)d_in[1];
    const float* li   = (const float*)d_in[2];
    const float* br   = (const float*)d_in[3];
    const float* bi   = (const float*)d_in[4];
    const float* rr   = (const float*)d_in[5];
    const float* ri   = (const float*)d_in[6];
    float2* out = (float2*)d_out;

    mps_mfma_kernel<<<dim3(256), dim3(256), 0, stream>>>(spin, lr, li, br, bi, rr, ri, out);
}

// Round 5
// 51.838 us; speedup vs baseline: 4.4598x; 1.1154x over previous
//
#include <hip/hip_runtime.h>
#include <stdint.h>

// MPS amplitude via MFMA, round 5.
// Pre-kernel converts bulk (62 sites x 2 spins, fp32) into MFMA-ready bf16
// hi/lo B-fragments in d_ws (16KB/site, 992KB total, L2-resident).
// Main kernel: 256 blocks x 512 threads (8 waves = 2/SIMD).
// Waves split (mt, nt, spin): each computes one spin's 16x16 C tile
// (12 MFMAs: 3-term split x 2 K-halves), winning spin-wave writes v.
// v stored in LDS as packed bf16 (vr,vi) hi/lo pairs (identical values to
// R4's consumer-side split): read as 8 conflict-free ds_read_b64, written
// as 8 conflict-free predicated ds_write_b32. One barrier per site.
// B fragments register-prefetched one site ahead from ws (global, L2).

typedef __attribute__((ext_vector_type(4))) float        f32x4;
typedef __attribute__((ext_vector_type(8))) short        s16x8;
typedef __attribute__((ext_vector_type(4))) unsigned int u32x4;
typedef __attribute__((ext_vector_type(2))) unsigned int u32x2;

__device__ __forceinline__ unsigned cvt_pk_bf16(float lo, float hi) {
    unsigned r;
    asm("v_cvt_pk_bf16_f32 %0, %1, %2" : "=v"(r) : "v"(lo), "v"(hi));
    return r;
}
__device__ __forceinline__ float lo_f(unsigned h) { return __uint_as_float(h << 16); }
__device__ __forceinline__ float hi_f(unsigned h) { return __uint_as_float(h & 0xFFFF0000u); }
__device__ __forceinline__ s16x8 frg(u32x4 x) { return __builtin_bit_cast(s16x8, x); }
#define MFMA16(A, B, C) __builtin_amdgcn_mfma_f32_16x16x32_bf16(frg(A), frg(B), C, 0, 0, 0)

// ws layout (u32 units), per site (stride 4096):
//   off = hl*2048 + s*1024 + kk*512 + g*128 + col*4 + q     (q = 0..3)
__global__ __launch_bounds__(256, 1) void mps_preconvert(
    const float* __restrict__ bulk_r, const float* __restrict__ bulk_i,
    unsigned* __restrict__ ws)
{
    const int site = blockIdx.x;          // 0..61
    const int tid  = threadIdx.x;
    const int ccol = tid & 31;
    const int c0   = tid >> 5;
    const float* br = bulk_r + (size_t)site * 2048 + ccol;
    const float* bi = bulk_i + (size_t)site * 2048 + ccol;
    unsigned* wsu = ws + (size_t)site * 4096;
    #pragma unroll
    for (int h = 0; h < 2; ++h) {
        const int c  = c0 + h * 8;
        const int s  = c >> 3;
        const int kk = (c >> 2) & 1;
        const int g  = c & 3;
        const int ub = kk * 16 + 2 * g;
        const float* R = br + s * 1024;
        const float* I = bi + s * 1024;
        float v0 = R[(ub + 0) * 32], v1 = I[(ub + 0) * 32];
        float v2 = R[(ub + 1) * 32], v3 = I[(ub + 1) * 32];
        float v4 = R[(ub + 8) * 32], v5 = I[(ub + 8) * 32];
        float v6 = R[(ub + 9) * 32], v7 = I[(ub + 9) * 32];
        unsigned h0 = cvt_pk_bf16(v0, v1), h1 = cvt_pk_bf16(v2, v3);
        unsigned h2 = cvt_pk_bf16(v4, v5), h3 = cvt_pk_bf16(v6, v7);
        unsigned l0 = cvt_pk_bf16(v0 - lo_f(h0), v1 - hi_f(h0));
        unsigned l1 = cvt_pk_bf16(v2 - lo_f(h1), v3 - hi_f(h1));
        unsigned l2 = cvt_pk_bf16(v4 - lo_f(h2), v5 - hi_f(h2));
        unsigned l3 = cvt_pk_bf16(v6 - lo_f(h3), v7 - hi_f(h3));
        const unsigned base = (unsigned)(s * 1024 + kk * 512 + g * 128 + ccol * 4);
        *(u32x4*)(wsu + base)        = (u32x4){h0, h1, h2, h3};
        *(u32x4*)(wsu + 2048 + base) = (u32x4){l0, l1, l2, l3};
    }
}

__global__ __launch_bounds__(512, 2) void mps_mfma2_kernel(
    const int*   __restrict__ spin,
    const float* __restrict__ left_r,  const float* __restrict__ left_i,
    const float* __restrict__ right_r, const float* __restrict__ right_i,
    const unsigned* __restrict__ ws,
    float2*      __restrict__ out)
{
    __shared__ unsigned Vst[2][32 * 68];   // [buf][e*68 + hl*32 + u], pad 4
    __shared__ float2 red[32][8];
    __shared__ unsigned smask[32][2];

    const int tid  = threadIdx.x;
    const int l    = tid & 63;
    const int wid  = tid >> 6;            // 0..7
    const int mt   = (wid >> 2) & 1;      // element half
    const int nt   = (wid >> 1) & 1;      // column half
    const int sw   = wid & 1;             // spin this wave computes
    const int lr16 = l & 15;
    const int lg   = l >> 4;
    const int ve   = mt * 16 + lr16;      // A-row (element) for V frags
    const int jc   = nt * 16 + lr16;      // C column
    const int blk  = blockIdx.x;

    // ---- spin masks ----
    if (tid < 32) {
        const int* sp = spin + ((size_t)(blk * 32 + tid)) * 64;
        unsigned a0 = 0, a1 = 0;
        #pragma unroll
        for (int k = 0; k < 32; ++k) a0 |= (unsigned)(sp[k] & 1) << k;
        #pragma unroll
        for (int k = 0; k < 32; ++k) a1 |= (unsigned)(sp[32 + k] & 1) << k;
        smask[tid][0] = a0; smask[tid][1] = a1;
    }

    // ---- init v = left[s0] as packed hi/lo ----
    {
        const int e  = tid & 31;
        const int j0 = (tid >> 5) * 2;    // 0..30
        const int s0 = spin[((size_t)(blk * 32 + e)) * 64] & 1;
        #pragma unroll
        for (int d = 0; d < 2; ++d) {
            const int j = j0 + d;
            const float vr = left_r[s0 * 32 + j], vi = left_i[s0 * 32 + j];
            const unsigned h  = cvt_pk_bf16(vr, vi);
            const unsigned lo = cvt_pk_bf16(vr - lo_f(h), vi - hi_f(h));
            Vst[0][e * 68 + j]      = h;
            Vst[0][e * 68 + 32 + j] = lo;
        }
    }

    // ---- issue site-0 B-fragment loads ----
    const unsigned* pb0 = ws + sw * 1024 + lg * 128 + jc * 4;
    u32x4 Ah0 = *(const u32x4*)(pb0);
    u32x4 Ah1 = *(const u32x4*)(pb0 + 512);
    u32x4 Al0 = *(const u32x4*)(pb0 + 2048);
    u32x4 Al1 = *(const u32x4*)(pb0 + 2560);
    u32x4 Bh0, Bh1, Bl0, Bl1;

    __syncthreads();

    // per-lane spin words for its 4 C-row elements
    unsigned em0[4], em1[4];
    #pragma unroll
    for (int r = 0; r < 4; ++r) {
        const int ee = mt * 16 + lg * 4 + r;
        em0[r] = smask[ee][0];
        em1[r] = smask[ee][1];
    }

    auto site = [&](int t, const unsigned* Vin, unsigned* Vout,
                    const u32x4& Ph0, const u32x4& Ph1,
                    const u32x4& Pl0, const u32x4& Pl1,
                    u32x4& Nh0, u32x4& Nh1, u32x4& Nl0, u32x4& Nl1) {
        // V fragment reads (8 x ds_read_b64, conflict-free)
        const unsigned* pv = Vin + ve * 68;
        const int u0 = 2 * lg;
        u32x2 a0 = *(const u32x2*)(pv + u0);
        u32x2 a1 = *(const u32x2*)(pv + u0 + 8);
        u32x2 a2 = *(const u32x2*)(pv + 16 + u0);
        u32x2 a3 = *(const u32x2*)(pv + 16 + u0 + 8);
        u32x2 b0 = *(const u32x2*)(pv + 32 + u0);
        u32x2 b1 = *(const u32x2*)(pv + 32 + u0 + 8);
        u32x2 b2 = *(const u32x2*)(pv + 48 + u0);
        u32x2 b3 = *(const u32x2*)(pv + 48 + u0 + 8);
        u32x4 Vh0 = (u32x4){a0.x, a0.y, a1.x, a1.y};
        u32x4 Vh1 = (u32x4){a2.x, a2.y, a3.x, a3.y};
        u32x4 Vl0 = (u32x4){b0.x, b0.y, b1.x, b1.y};
        u32x4 Vl1 = (u32x4){b2.x, b2.y, b3.x, b3.y};

        // prefetch next site's B fragments (consumed next call)
        {
            int tn = t + 1; if (tn > 61) tn = 61;
            const unsigned* pb = ws + (size_t)tn * 4096 + sw * 1024 + lg * 128 + jc * 4;
            Nh0 = *(const u32x4*)(pb);
            Nh1 = *(const u32x4*)(pb + 512);
            Nl0 = *(const u32x4*)(pb + 2048);
            Nl1 = *(const u32x4*)(pb + 2560);
        }

        // derive V_r = (vr,-vi) and V_i = (vi,vr) for hi and lo
        u32x4 r_h0, r_h1, r_l0, r_l1, i_h0, i_h1, i_l0, i_l1;
        #pragma unroll
        for (int q = 0; q < 4; ++q) {
            r_h0[q] = Vh0[q] ^ 0x80000000u;
            r_h1[q] = Vh1[q] ^ 0x80000000u;
            r_l0[q] = Vl0[q] ^ 0x80000000u;
            r_l1[q] = Vl1[q] ^ 0x80000000u;
            i_h0[q] = __builtin_amdgcn_alignbit(Vh0[q], Vh0[q], 16);
            i_h1[q] = __builtin_amdgcn_alignbit(Vh1[q], Vh1[q], 16);
            i_l0[q] = __builtin_amdgcn_alignbit(Vl0[q], Vl0[q], 16);
            i_l1[q] = __builtin_amdgcn_alignbit(Vl1[q], Vl1[q], 16);
        }

        f32x4 ar = {0.f, 0.f, 0.f, 0.f};
        f32x4 ai = {0.f, 0.f, 0.f, 0.f};
        ar = MFMA16(r_h0, Ph0, ar); ar = MFMA16(r_h0, Pl0, ar); ar = MFMA16(r_l0, Ph0, ar);
        ar = MFMA16(r_h1, Ph1, ar); ar = MFMA16(r_h1, Pl1, ar); ar = MFMA16(r_l1, Ph1, ar);
        ai = MFMA16(i_h0, Ph0, ai); ai = MFMA16(i_h0, Pl0, ai); ai = MFMA16(i_l0, Ph0, ai);
        ai = MFMA16(i_h1, Ph1, ai); ai = MFMA16(i_h1, Pl1, ai); ai = MFMA16(i_l1, Ph1, ai);

        // winning spin-wave packs and writes v_next
        const int bp = t + 1;
        #pragma unroll
        for (int r = 0; r < 4; ++r) {
            const unsigned mw = (bp < 32) ? em0[r] : em1[r];
            const int sb = (int)((mw >> (bp & 31)) & 1u);
            if (sb == sw) {
                const int ee = mt * 16 + lg * 4 + r;
                const unsigned h  = cvt_pk_bf16(ar[r], ai[r]);
                const unsigned lo = cvt_pk_bf16(ar[r] - lo_f(h), ai[r] - hi_f(h));
                Vout[ee * 68 + jc]      = h;
                Vout[ee * 68 + 32 + jc] = lo;
            }
        }
        __syncthreads();
    };

    for (int tt = 0; tt < 31; ++tt) {
        site(2 * tt,     Vst[0], Vst[1], Ah0, Ah1, Al0, Al1, Bh0, Bh1, Bl0, Bl1);
        site(2 * tt + 1, Vst[1], Vst[0], Bh0, Bh1, Bl0, Bl1, Ah0, Ah1, Al0, Al1);
    }

    // ---- right contraction ----
    if (tid < 256) {
        const int e = tid & 31, jg = tid >> 5;
        const unsigned sR = (smask[e][1] >> 31) & 1u;
        const float* Rr = right_r + sR * 32;
        const float* Ri = right_i + sR * 32;
        float pr = 0.f, pi = 0.f;
        #pragma unroll
        for (int d = 0; d < 4; ++d) {
            const int j = jg * 4 + d;
            const unsigned h  = Vst[0][e * 68 + j];
            const unsigned lo = Vst[0][e * 68 + 32 + j];
            const float vr = lo_f(h) + lo_f(lo);
            const float vi = hi_f(h) + hi_f(lo);
            pr += vr * Rr[j] - vi * Ri[j];
            pi += vr * Ri[j] + vi * Rr[j];
        }
        red[e][jg] = make_float2(pr, pi);
    }
    __syncthreads();
    if (tid < 32) {
        float2 a = red[tid][0];
        #pragma unroll
        for (int k = 1; k < 8; ++k) { a.x += red[tid][k].x; a.y += red[tid][k].y; }
        out[blk * 32 + tid] = a;
    }
}

// ---------------- fallback (round-4 kernel) if ws too small ----------------
__global__ __launch_bounds__(256, 1) void mps_mfma_kernel_fb(
    const int*   __restrict__ spin,
    const float* __restrict__ left_r,  const float* __restrict__ left_i,
    const float* __restrict__ bulk_r,  const float* __restrict__ bulk_i,
    const float* __restrict__ right_r, const float* __restrict__ right_i,
    float2*      __restrict__ out)
{
    __shared__ unsigned short Bf[2][2][2][2][4][32][8];
    __shared__ float vT[2][64][33];
    __shared__ float2 red[32][8];
    __shared__ unsigned smask[32][2];

    const int tid  = threadIdx.x;
    const int l    = tid & 63;
    const int wid  = tid >> 6;
    const int mt   = wid >> 1;
    const int nt   = wid & 1;
    const int lr16 = l & 15;
    const int lg   = l >> 4;
    const int ve   = mt * 16 + lr16;
    const int jc   = nt * 16 + lr16;
    const int blk  = blockIdx.x;
    const int ccol = tid & 31;
    const int c0   = tid >> 5;

    auto convert = [&](int site, int buf) {
        const float* br = bulk_r + (size_t)site * 2048 + ccol;
        const float* bi = bulk_i + (size_t)site * 2048 + ccol;
        #pragma unroll
        for (int h = 0; h < 2; ++h) {
            const int c  = c0 + h * 8;
            const int s  = c >> 3;
            const int kk = (c >> 2) & 1;
            const int g  = c & 3;
            const int ub = kk * 16 + 2 * g;
            const float* R = br + s * 1024;
            const float* I = bi + s * 1024;
            float v0 = R[(ub + 0) * 32], v1 = I[(ub + 0) * 32];
            float v2 = R[(ub + 1) * 32], v3 = I[(ub + 1) * 32];
            float v4 = R[(ub + 8) * 32], v5 = I[(ub + 8) * 32];
            float v6 = R[(ub + 9) * 32], v7 = I[(ub + 9) * 32];
            unsigned h0 = cvt_pk_bf16(v0, v1), h1 = cvt_pk_bf16(v2, v3);
            unsigned h2 = cvt_pk_bf16(v4, v5), h3 = cvt_pk_bf16(v6, v7);
            unsigned l0 = cvt_pk_bf16(v0 - lo_f(h0), v1 - hi_f(h0));
            unsigned l1 = cvt_pk_bf16(v2 - lo_f(h1), v3 - hi_f(h1));
            unsigned l2 = cvt_pk_bf16(v4 - lo_f(h2), v5 - hi_f(h2));
            unsigned l3 = cvt_pk_bf16(v6 - lo_f(h3), v7 - hi_f(h3));
            *(u32x4*)&Bf[buf][0][s][kk][g][ccol][0] = (u32x4){h0, h1, h2, h3};
            *(u32x4*)&Bf[buf][1][s][kk][g][ccol][0] = (u32x4){l0, l1, l2, l3};
        }
    };

    if (tid < 32) {
        const int* sp = spin + ((size_t)(blk * 32 + tid)) * 64;
        unsigned a0 = 0, a1 = 0;
        #pragma unroll
        for (int k = 0; k < 32; ++k) a0 |= (unsigned)(sp[k] & 1) << k;
        #pragma unroll
        for (int k = 0; k < 32; ++k) a1 |= (unsigned)(sp[32 + k] & 1) << k;
        smask[tid][0] = a0; smask[tid][1] = a1;
    }
    {
        const int e = tid & 31, jg = tid >> 5;
        const int s0 = spin[((size_t)(blk * 32 + e)) * 64] & 1;
        #pragma unroll
        for (int d = 0; d < 4; ++d) {
            const int j = jg * 4 + d;
            vT[0][2 * j    ][e] = left_r[s0 * 32 + j];
            vT[0][2 * j + 1][e] = left_i[s0 * 32 + j];
        }
    }
    convert(0, 0);
    __syncthreads();

    unsigned em0[4], em1[4];
    #pragma unroll
    for (int r = 0; r < 4; ++r) {
        const int ee = mt * 16 + lg * 4 + r;
        em0[r] = smask[ee][0];
        em1[r] = smask[ee][1];
    }

    #pragma unroll 2
    for (int t = 0; t < 62; ++t) {
        const int b = t & 1;
        float f[16];
        #pragma unroll
        for (int kk = 0; kk < 2; ++kk)
            #pragma unroll
            for (int q = 0; q < 2; ++q)
                #pragma unroll
                for (int r = 0; r < 4; ++r)
                    f[kk * 8 + q * 4 + r] = vT[b][kk * 32 + q * 16 + 4 * lg + r][ve];

        u32x4 Vh[2], Vl[2];
        #pragma unroll
        for (int kk = 0; kk < 2; ++kk)
            #pragma unroll
            for (int q = 0; q < 2; ++q) {
                const float a = f[kk*8+q*4+0], c2 = f[kk*8+q*4+1];
                const float d2 = f[kk*8+q*4+2], e2 = f[kk*8+q*4+3];
                const unsigned h0 = cvt_pk_bf16(a, c2);
                const unsigned h1 = cvt_pk_bf16(d2, e2);
                Vh[kk][q*2+0] = h0;
                Vh[kk][q*2+1] = h1;
                Vl[kk][q*2+0] = cvt_pk_bf16(a - lo_f(h0), c2 - hi_f(h0));
                Vl[kk][q*2+1] = cvt_pk_bf16(d2 - lo_f(h1), e2 - hi_f(h1));
            }

        u32x4 Bh[2][2], Bl[2][2];
        #pragma unroll
        for (int s = 0; s < 2; ++s)
            #pragma unroll
            for (int kk = 0; kk < 2; ++kk) {
                Bh[s][kk] = *(const u32x4*)&Bf[b][0][s][kk][lg][jc][0];
                Bl[s][kk] = *(const u32x4*)&Bf[b][1][s][kk][lg][jc][0];
            }

        if (t < 61) convert(t + 1, b ^ 1);

        f32x4 ar[2] = {{0,0,0,0},{0,0,0,0}};
        f32x4 ai[2] = {{0,0,0,0},{0,0,0,0}};
        #pragma unroll
        for (int kk = 0; kk < 2; ++kk) {
            u32x4 vh, vl;
            #pragma unroll
            for (int q = 0; q < 4; ++q) {
                vh[q] = Vh[kk][q] ^ 0x80000000u;
                vl[q] = Vl[kk][q] ^ 0x80000000u;
            }
            #pragma unroll
            for (int s = 0; s < 2; ++s) {
                ar[s] = MFMA16(vh, Bh[s][kk], ar[s]);
                ar[s] = MFMA16(vh, Bl[s][kk], ar[s]);
                ar[s] = MFMA16(vl, Bh[s][kk], ar[s]);
            }
        }
        #pragma unroll
        for (int kk = 0; kk < 2; ++kk) {
            u32x4 vh, vl;
            #pragma unroll
            for (int q = 0; q < 4; ++q) {
                vh[q] = __builtin_amdgcn_alignbit(Vh[kk][q], Vh[kk][q], 16);
                vl[q] = __builtin_amdgcn_alignbit(Vl[kk][q], Vl[kk][q], 16);
            }
            #pragma unroll
            for (int s = 0; s < 2; ++s) {
                ai[s] = MFMA16(vh, Bh[s][kk], ai[s]);
                ai[s] = MFMA16(vh, Bl[s][kk], ai[s]);
                ai[s] = MFMA16(vl, Bh[s][kk], ai[s]);
            }
        }

        const int bp = t + 1;
        #pragma unroll
        for (int r = 0; r < 4; ++r) {
            const unsigned mw = (bp < 32) ? em0[r] : em1[r];
            const bool sb = (mw >> (bp & 31)) & 1u;
            const int ee = mt * 16 + lg * 4 + r;
            vT[b ^ 1][2 * jc    ][ee] = sb ? ar[1][r] : ar[0][r];
            vT[b ^ 1][2 * jc + 1][ee] = sb ? ai[1][r] : ai[0][r];
        }
        __syncthreads();
    }

    {
        const int e = tid & 31, jg = tid >> 5;
        const unsigned sR = (smask[e][1] >> 31) & 1u;
        const float* Rr = right_r + sR * 32;
        const float* Ri = right_i + sR * 32;
        float pr = 0.f, pi = 0.f;
        #pragma unroll
        for (int d = 0; d < 4; ++d) {
            const int j = jg * 4 + d;
            const float vr = vT[0][2 * j][e], vi = vT[0][2 * j + 1][e];
            pr += vr * Rr[j] - vi * Ri[j];
            pi += vr * Ri[j] + vi * Rr[j];
        }
        red[e][jg] = make_float2(pr, pi);
    }
    __syncthreads();
    if (tid < 32) {
        float2 a = red[tid][0];
        #pragma unroll
        for (int k = 1; k < 8; ++k) { a.x += red[tid][k].x; a.y += red[tid][k].y; }
        out[blk * 32 + tid] = a;
    }
}

extern "C" void kernel_launch(void* const* d_in, const int* in_sizes, int n_in,
                              void* d_out, int out_size, void* d_ws, size_t ws_size,
                              hipStream_t stream)
{
    const int*   spin = (const int*)  d_in[0];
    const float* lr   = (const float*)d_in[1];
    const float* li   = (const float*)d_in[2];
    const float* br   = (const float*)d_in[3];
    const float* bi   = (const float*)d_in[4];
    const float* rr   = (const float*)d_in[5];
    const float* ri   = (const float*)d_in[6];
    float2* out = (float2*)d_out;

    const size_t WS_NEEDED = (size_t)62 * 16384;   // 992 KB
    if (ws_size >= WS_NEEDED) {
        unsigned* ws = (unsigned*)d_ws;
        mps_preconvert<<<dim3(62), dim3(256), 0, stream>>>(br, bi, ws);
        mps_mfma2_kernel<<<dim3(256), dim3(512), 0, stream>>>(spin, lr, li, rr, ri, ws, out);
    } else {
        mps_mfma_kernel_fb<<<dim3(256), dim3(256), 0, stream>>>(spin, lr, li, br, bi, rr, ri, out);
    }
}

// Round 6
// 51.210 us; speedup vs baseline: 4.5145x; 1.0123x over previous
//
#include <hip/hip_runtime.h>
#include <stdint.h>

// MPS amplitude via MFMA, round 6.
// Pre-kernel converts bulk (62 sites x 2 spins) to bf16 hi/lo B-fragments in
// d_ws (16KB/site, 992KB, L2-resident). Main kernel: 256 blocks x 512 threads
// (8 waves = mt x nt x sw). Per site each wave computes one spin's 16x16 tile
// (12 MFMAs, two parallel kk-chains); winning spin-wave writes v.
// KEY CHANGE vs R5: site-loop barriers are lgkmcnt-only (raw s_barrier), so
// the next-site B-fragment register prefetch stays in flight ACROSS the
// barrier (T4 counted-wait idiom); __syncthreads()'s vmcnt(0) drain was
// defeating the pipeline (VGPR_Count=44 evidence).
// v stored in LDS q-permuted so each lane's fragment = one ds_read_b128.

typedef __attribute__((ext_vector_type(4))) float        f32x4;
typedef __attribute__((ext_vector_type(8))) short        s16x8;
typedef __attribute__((ext_vector_type(4))) unsigned int u32x4;

__device__ __forceinline__ unsigned cvt_pk_bf16(float lo, float hi) {
    unsigned r;
    asm("v_cvt_pk_bf16_f32 %0, %1, %2" : "=v"(r) : "v"(lo), "v"(hi));
    return r;
}
__device__ __forceinline__ float lo_f(unsigned h) { return __uint_as_float(h << 16); }
__device__ __forceinline__ float hi_f(unsigned h) { return __uint_as_float(h & 0xFFFF0000u); }
__device__ __forceinline__ s16x8 frg(u32x4 x) { return __builtin_bit_cast(s16x8, x); }
#define MFMA16(A, B, C) __builtin_amdgcn_mfma_f32_16x16x32_bf16(frg(A), frg(B), C, 0, 0, 0)

// storage permutation: word u (complex col, K-pair) -> contiguous frag slots
__device__ __forceinline__ int qperm(int u) {
    return (u >> 4) * 16 + ((u >> 1) & 3) * 4 + ((u >> 3) & 1) * 2 + (u & 1);
}

// ws layout (u32 units), per site (stride 4096):
//   off = hl*2048 + s*1024 + kk*512 + g*128 + col*4 + q     (q = 0..3)
__global__ __launch_bounds__(256, 1) void mps_preconvert(
    const float* __restrict__ bulk_r, const float* __restrict__ bulk_i,
    unsigned* __restrict__ ws)
{
    const int site = blockIdx.x;          // 0..61
    const int tid  = threadIdx.x;
    const int ccol = tid & 31;
    const int c0   = tid >> 5;
    const float* br = bulk_r + (size_t)site * 2048 + ccol;
    const float* bi = bulk_i + (size_t)site * 2048 + ccol;
    unsigned* wsu = ws + (size_t)site * 4096;
    #pragma unroll
    for (int h = 0; h < 2; ++h) {
        const int c  = c0 + h * 8;
        const int s  = c >> 3;
        const int kk = (c >> 2) & 1;
        const int g  = c & 3;
        const int ub = kk * 16 + 2 * g;
        const float* R = br + s * 1024;
        const float* I = bi + s * 1024;
        float v0 = R[(ub + 0) * 32], v1 = I[(ub + 0) * 32];
        float v2 = R[(ub + 1) * 32], v3 = I[(ub + 1) * 32];
        float v4 = R[(ub + 8) * 32], v5 = I[(ub + 8) * 32];
        float v6 = R[(ub + 9) * 32], v7 = I[(ub + 9) * 32];
        unsigned h0 = cvt_pk_bf16(v0, v1), h1 = cvt_pk_bf16(v2, v3);
        unsigned h2 = cvt_pk_bf16(v4, v5), h3 = cvt_pk_bf16(v6, v7);
        unsigned l0 = cvt_pk_bf16(v0 - lo_f(h0), v1 - hi_f(h0));
        unsigned l1 = cvt_pk_bf16(v2 - lo_f(h1), v3 - hi_f(h1));
        unsigned l2 = cvt_pk_bf16(v4 - lo_f(h2), v5 - hi_f(h2));
        unsigned l3 = cvt_pk_bf16(v6 - lo_f(h3), v7 - hi_f(h3));
        const unsigned base = (unsigned)(s * 1024 + kk * 512 + g * 128 + ccol * 4);
        *(u32x4*)(wsu + base)        = (u32x4){h0, h1, h2, h3};
        *(u32x4*)(wsu + 2048 + base) = (u32x4){l0, l1, l2, l3};
    }
}

__global__ __launch_bounds__(512, 2) void mps_mfma2_kernel(
    const int*   __restrict__ spin,
    const float* __restrict__ left_r,  const float* __restrict__ left_i,
    const float* __restrict__ right_r, const float* __restrict__ right_i,
    const unsigned* __restrict__ ws,
    float2*      __restrict__ out)
{
    __shared__ unsigned Vst[2][32 * 68];   // [buf][e*68 + {q:0..31 hi, 32+q lo}]
    __shared__ float2 red[32][8];
    __shared__ unsigned smask[32][2];

    const int tid  = threadIdx.x;
    const int l    = tid & 63;
    const int wid  = tid >> 6;            // 0..7
    const int mt   = (wid >> 2) & 1;      // element half
    const int nt   = (wid >> 1) & 1;      // column half
    const int sw   = wid & 1;             // spin this wave computes
    const int lr16 = l & 15;
    const int lg   = l >> 4;
    const int ve   = mt * 16 + lr16;      // A-row (element) for V frags
    const int jc   = nt * 16 + lr16;      // C column
    const int qjc  = qperm(jc);           // storage slot for column jc
    const int blk  = blockIdx.x;

    // ---- spin masks ----
    if (tid < 32) {
        const int* sp = spin + ((size_t)(blk * 32 + tid)) * 64;
        unsigned a0 = 0, a1 = 0;
        #pragma unroll
        for (int k = 0; k < 32; ++k) a0 |= (unsigned)(sp[k] & 1) << k;
        #pragma unroll
        for (int k = 0; k < 32; ++k) a1 |= (unsigned)(sp[32 + k] & 1) << k;
        smask[tid][0] = a0; smask[tid][1] = a1;
    }

    // ---- init v = left[s0] as packed hi/lo (q-permuted) ----
    {
        const int e  = tid & 31;
        const int j0 = (tid >> 5) * 2;    // 0..30
        const int s0 = spin[((size_t)(blk * 32 + e)) * 64] & 1;
        #pragma unroll
        for (int d = 0; d < 2; ++d) {
            const int j = j0 + d;
            const int qj = qperm(j);
            const float vr = left_r[s0 * 32 + j], vi = left_i[s0 * 32 + j];
            const unsigned h  = cvt_pk_bf16(vr, vi);
            const unsigned lo = cvt_pk_bf16(vr - lo_f(h), vi - hi_f(h));
            Vst[0][e * 68 + qj]      = h;
            Vst[0][e * 68 + 32 + qj] = lo;
        }
    }

    // ---- issue site-0 B-fragment loads (stay in flight across barrier) ----
    const unsigned* pb0 = ws + sw * 1024 + lg * 128 + jc * 4;
    u32x4 Ah0 = *(const u32x4*)(pb0);
    u32x4 Ah1 = *(const u32x4*)(pb0 + 512);
    u32x4 Al0 = *(const u32x4*)(pb0 + 2048);
    u32x4 Al1 = *(const u32x4*)(pb0 + 2560);
    u32x4 Bh0, Bh1, Bl0, Bl1;

    asm volatile("s_waitcnt lgkmcnt(0)" ::: "memory");
    __builtin_amdgcn_s_barrier();
    __builtin_amdgcn_sched_barrier(0);

    // per-lane spin words for its 4 C-row elements
    unsigned em0[4], em1[4];
    #pragma unroll
    for (int r = 0; r < 4; ++r) {
        const int ee = mt * 16 + lg * 4 + r;
        em0[r] = smask[ee][0];
        em1[r] = smask[ee][1];
    }

    auto site = [&](int t, const unsigned* Vin, unsigned* Vout,
                    const u32x4& Ph0, const u32x4& Ph1,
                    const u32x4& Pl0, const u32x4& Pl1,
                    u32x4& Nh0, u32x4& Nh1, u32x4& Nl0, u32x4& Nl1) {
        // prefetch next site's B fragments (consumed next call; loads remain
        // outstanding across the lgkm-only barrier below)
        {
            int tn = t + 1; if (tn > 61) tn = 61;
            const unsigned* pb = ws + (size_t)tn * 4096 + sw * 1024 + lg * 128 + jc * 4;
            Nh0 = *(const u32x4*)(pb);
            Nh1 = *(const u32x4*)(pb + 512);
            Nl0 = *(const u32x4*)(pb + 2048);
            Nl1 = *(const u32x4*)(pb + 2560);
        }

        // V fragment reads: 4 x ds_read_b128 (q-permuted contiguous slots)
        const unsigned* pv = Vin + ve * 68 + 4 * lg;
        u32x4 Vh0 = *(const u32x4*)(pv);
        u32x4 Vh1 = *(const u32x4*)(pv + 16);
        u32x4 Vl0 = *(const u32x4*)(pv + 32);
        u32x4 Vl1 = *(const u32x4*)(pv + 48);

        // derive V_r = (vr,-vi) and V_i = (vi,vr) for hi and lo
        u32x4 r_h0, r_h1, r_l0, r_l1, i_h0, i_h1, i_l0, i_l1;
        #pragma unroll
        for (int q = 0; q < 4; ++q) {
            r_h0[q] = Vh0[q] ^ 0x80000000u;
            r_h1[q] = Vh1[q] ^ 0x80000000u;
            r_l0[q] = Vl0[q] ^ 0x80000000u;
            r_l1[q] = Vl1[q] ^ 0x80000000u;
            i_h0[q] = __builtin_amdgcn_alignbit(Vh0[q], Vh0[q], 16);
            i_h1[q] = __builtin_amdgcn_alignbit(Vh1[q], Vh1[q], 16);
            i_l0[q] = __builtin_amdgcn_alignbit(Vl0[q], Vl0[q], 16);
            i_l1[q] = __builtin_amdgcn_alignbit(Vl1[q], Vl1[q], 16);
        }

        // two parallel kk-chains per output (dep depth 3)
        f32x4 arA = {0.f,0.f,0.f,0.f}, arB = {0.f,0.f,0.f,0.f};
        f32x4 aiA = {0.f,0.f,0.f,0.f}, aiB = {0.f,0.f,0.f,0.f};
        arA = MFMA16(r_h0, Ph0, arA); arA = MFMA16(r_h0, Pl0, arA); arA = MFMA16(r_l0, Ph0, arA);
        arB = MFMA16(r_h1, Ph1, arB); arB = MFMA16(r_h1, Pl1, arB); arB = MFMA16(r_l1, Ph1, arB);
        aiA = MFMA16(i_h0, Ph0, aiA); aiA = MFMA16(i_h0, Pl0, aiA); aiA = MFMA16(i_l0, Ph0, aiA);
        aiB = MFMA16(i_h1, Ph1, aiB); aiB = MFMA16(i_h1, Pl1, aiB); aiB = MFMA16(i_l1, Ph1, aiB);
        f32x4 ar = arA + arB;
        f32x4 ai = aiA + aiB;

        // winning spin-wave packs and writes v_next (q-permuted)
        const int bp = t + 1;
        #pragma unroll
        for (int r = 0; r < 4; ++r) {
            const unsigned mw = (bp < 32) ? em0[r] : em1[r];
            const int sb = (int)((mw >> (bp & 31)) & 1u);
            if (sb == sw) {
                const int ee = mt * 16 + lg * 4 + r;
                const unsigned h  = cvt_pk_bf16(ar[r], ai[r]);
                const unsigned lo = cvt_pk_bf16(ar[r] - lo_f(h), ai[r] - hi_f(h));
                Vout[ee * 68 + qjc]      = h;
                Vout[ee * 68 + 32 + qjc] = lo;
            }
        }

        // lgkm-only barrier: LDS (v exchange) visible; B prefetch stays in flight
        asm volatile("s_waitcnt lgkmcnt(0)" ::: "memory");
        __builtin_amdgcn_s_barrier();
        __builtin_amdgcn_sched_barrier(0);
    };

    #pragma unroll 1
    for (int tt = 0; tt < 31; ++tt) {
        site(2 * tt,     Vst[0], Vst[1], Ah0, Ah1, Al0, Al1, Bh0, Bh1, Bl0, Bl1);
        site(2 * tt + 1, Vst[1], Vst[0], Bh0, Bh1, Bl0, Bl1, Ah0, Ah1, Al0, Al1);
    }

    // ---- right contraction ----
    if (tid < 256) {
        const int e = tid & 31, jg = tid >> 5;
        const unsigned sR = (smask[e][1] >> 31) & 1u;
        const float* Rr = right_r + sR * 32;
        const float* Ri = right_i + sR * 32;
        float pr = 0.f, pi = 0.f;
        #pragma unroll
        for (int d = 0; d < 4; ++d) {
            const int j = jg * 4 + d;
            const int qj = qperm(j);
            const unsigned h  = Vst[0][e * 68 + qj];
            const unsigned lo = Vst[0][e * 68 + 32 + qj];
            const float vr = lo_f(h) + lo_f(lo);
            const float vi = hi_f(h) + hi_f(lo);
            pr += vr * Rr[j] - vi * Ri[j];
            pi += vr * Ri[j] + vi * Rr[j];
        }
        red[e][jg] = make_float2(pr, pi);
    }
    __syncthreads();
    if (tid < 32) {
        float2 a = red[tid][0];
        #pragma unroll
        for (int k = 1; k < 8; ++k) { a.x += red[tid][k].x; a.y += red[tid][k].y; }
        out[blk * 32 + tid] = a;
    }
}

// ---------------- fallback (round-4 kernel) if ws too small ----------------
typedef __attribute__((ext_vector_type(2))) unsigned int u32x2;
__global__ __launch_bounds__(256, 1) void mps_mfma_kernel_fb(
    const int*   __restrict__ spin,
    const float* __restrict__ left_r,  const float* __restrict__ left_i,
    const float* __restrict__ bulk_r,  const float* __restrict__ bulk_i,
    const float* __restrict__ right_r, const float* __restrict__ right_i,
    float2*      __restrict__ out)
{
    __shared__ unsigned short Bf[2][2][2][2][4][32][8];
    __shared__ float vT[2][64][33];
    __shared__ float2 red[32][8];
    __shared__ unsigned smask[32][2];

    const int tid  = threadIdx.x;
    const int l    = tid & 63;
    const int wid  = tid >> 6;
    const int mt   = wid >> 1;
    const int nt   = wid & 1;
    const int lr16 = l & 15;
    const int lg   = l >> 4;
    const int ve   = mt * 16 + lr16;
    const int jc   = nt * 16 + lr16;
    const int blk  = blockIdx.x;
    const int ccol = tid & 31;
    const int c0   = tid >> 5;

    auto convert = [&](int site, int buf) {
        const float* br = bulk_r + (size_t)site * 2048 + ccol;
        const float* bi = bulk_i + (size_t)site * 2048 + ccol;
        #pragma unroll
        for (int h = 0; h < 2; ++h) {
            const int c  = c0 + h * 8;
            const int s  = c >> 3;
            const int kk = (c >> 2) & 1;
            const int g  = c & 3;
            const int ub = kk * 16 + 2 * g;
            const float* R = br + s * 1024;
            const float* I = bi + s * 1024;
            float v0 = R[(ub + 0) * 32], v1 = I[(ub + 0) * 32];
            float v2 = R[(ub + 1) * 32], v3 = I[(ub + 1) * 32];
            float v4 = R[(ub + 8) * 32], v5 = I[(ub + 8) * 32];
            float v6 = R[(ub + 9) * 32], v7 = I[(ub + 9) * 32];
            unsigned h0 = cvt_pk_bf16(v0, v1), h1 = cvt_pk_bf16(v2, v3);
            unsigned h2 = cvt_pk_bf16(v4, v5), h3 = cvt_pk_bf16(v6, v7);
            unsigned l0 = cvt_pk_bf16(v0 - lo_f(h0), v1 - hi_f(h0));
            unsigned l1 = cvt_pk_bf16(v2 - lo_f(h1), v3 - hi_f(h1));
            unsigned l2 = cvt_pk_bf16(v4 - lo_f(h2), v5 - hi_f(h2));
            unsigned l3 = cvt_pk_bf16(v6 - lo_f(h3), v7 - hi_f(h3));
            *(u32x4*)&Bf[buf][0][s][kk][g][ccol][0] = (u32x4){h0, h1, h2, h3};
            *(u32x4*)&Bf[buf][1][s][kk][g][ccol][0] = (u32x4){l0, l1, l2, l3};
        }
    };

    if (tid < 32) {
        const int* sp = spin + ((size_t)(blk * 32 + tid)) * 64;
        unsigned a0 = 0, a1 = 0;
        #pragma unroll
        for (int k = 0; k < 32; ++k) a0 |= (unsigned)(sp[k] & 1) << k;
        #pragma unroll
        for (int k = 0; k < 32; ++k) a1 |= (unsigned)(sp[32 + k] & 1) << k;
        smask[tid][0] = a0; smask[tid][1] = a1;
    }
    {
        const int e = tid & 31, jg = tid >> 5;
        const int s0 = spin[((size_t)(blk * 32 + e)) * 64] & 1;
        #pragma unroll
        for (int d = 0; d < 4; ++d) {
            const int j = jg * 4 + d;
            vT[0][2 * j    ][e] = left_r[s0 * 32 + j];
            vT[0][2 * j + 1][e] = left_i[s0 * 32 + j];
        }
    }
    convert(0, 0);
    __syncthreads();

    unsigned em0[4], em1[4];
    #pragma unroll
    for (int r = 0; r < 4; ++r) {
        const int ee = mt * 16 + lg * 4 + r;
        em0[r] = smask[ee][0];
        em1[r] = smask[ee][1];
    }

    #pragma unroll 2
    for (int t = 0; t < 62; ++t) {
        const int b = t & 1;
        float f[16];
        #pragma unroll
        for (int kk = 0; kk < 2; ++kk)
            #pragma unroll
            for (int q = 0; q < 2; ++q)
                #pragma unroll
                for (int r = 0; r < 4; ++r)
                    f[kk * 8 + q * 4 + r] = vT[b][kk * 32 + q * 16 + 4 * lg + r][ve];

        u32x4 Vh[2], Vl[2];
        #pragma unroll
        for (int kk = 0; kk < 2; ++kk)
            #pragma unroll
            for (int q = 0; q < 2; ++q) {
                const float a = f[kk*8+q*4+0], c2 = f[kk*8+q*4+1];
                const float d2 = f[kk*8+q*4+2], e2 = f[kk*8+q*4+3];
                const unsigned h0 = cvt_pk_bf16(a, c2);
                const unsigned h1 = cvt_pk_bf16(d2, e2);
                Vh[kk][q*2+0] = h0;
                Vh[kk][q*2+1] = h1;
                Vl[kk][q*2+0] = cvt_pk_bf16(a - lo_f(h0), c2 - hi_f(h0));
                Vl[kk][q*2+1] = cvt_pk_bf16(d2 - lo_f(h1), e2 - hi_f(h1));
            }

        u32x4 Bh[2][2], Bl[2][2];
        #pragma unroll
        for (int s = 0; s < 2; ++s)
            #pragma unroll
            for (int kk = 0; kk < 2; ++kk) {
                Bh[s][kk] = *(const u32x4*)&Bf[b][0][s][kk][lg][jc][0];
                Bl[s][kk] = *(const u32x4*)&Bf[b][1][s][kk][lg][jc][0];
            }

        if (t < 61) convert(t + 1, b ^ 1);

        f32x4 ar[2] = {{0,0,0,0},{0,0,0,0}};
        f32x4 ai[2] = {{0,0,0,0},{0,0,0,0}};
        #pragma unroll
        for (int kk = 0; kk < 2; ++kk) {
            u32x4 vh, vl;
            #pragma unroll
            for (int q = 0; q < 4; ++q) {
                vh[q] = Vh[kk][q] ^ 0x80000000u;
                vl[q] = Vl[kk][q] ^ 0x80000000u;
            }
            #pragma unroll
            for (int s = 0; s < 2; ++s) {
                ar[s] = MFMA16(vh, Bh[s][kk], ar[s]);
                ar[s] = MFMA16(vh, Bl[s][kk], ar[s]);
                ar[s] = MFMA16(vl, Bh[s][kk], ar[s]);
            }
        }
        #pragma unroll
        for (int kk = 0; kk < 2; ++kk) {
            u32x4 vh, vl;
            #pragma unroll
            for (int q = 0; q < 4; ++q) {
                vh[q] = __builtin_amdgcn_alignbit(Vh[kk][q], Vh[kk][q], 16);
                vl[q] = __builtin_amdgcn_alignbit(Vl[kk][q], Vl[kk][q], 16);
            }
            #pragma unroll
            for (int s = 0; s < 2; ++s) {
                ai[s] = MFMA16(vh, Bh[s][kk], ai[s]);
                ai[s] = MFMA16(vh, Bl[s][kk], ai[s]);
                ai[s] = MFMA16(vl, Bh[s][kk], ai[s]);
            }
        }

        const int bp = t + 1;
        #pragma unroll
        for (int r = 0; r < 4; ++r) {
            const unsigned mw = (bp < 32) ? em0[r] : em1[r];
            const bool sb = (mw >> (bp & 31)) & 1u;
            const int ee = mt * 16 + lg * 4 + r;
            vT[b ^ 1][2 * jc    ][ee] = sb ? ar[1][r] : ar[0][r];
            vT[b ^ 1][2 * jc + 1][ee] = sb ? ai[1][r] : ai[0][r];
        }
        __syncthreads();
    }

    {
        const int e = tid & 31, jg = tid >> 5;
        const unsigned sR = (smask[e][1] >> 31) & 1u;
        const float* Rr = right_r + sR * 32;
        const float* Ri = right_i + sR * 32;
        float pr = 0.f, pi = 0.f;
        #pragma unroll
        for (int d = 0; d < 4; ++d) {
            const int j = jg * 4 + d;
            const float vr = vT[0][2 * j][e], vi = vT[0][2 * j + 1][e];
            pr += vr * Rr[j] - vi * Ri[j];
            pi += vr * Ri[j] + vi * Rr[j];
        }
        red[e][jg] = make_float2(pr, pi);
    }
    __syncthreads();
    if (tid < 32) {
        float2 a = red[tid][0];
        #pragma unroll
        for (int k = 1; k < 8; ++k) { a.x += red[tid][k].x; a.y += red[tid][k].y; }
        out[blk * 32 + tid] = a;
    }
}

extern "C" void kernel_launch(void* const* d_in, const int* in_sizes, int n_in,
                              void* d_out, int out_size, void* d_ws, size_t ws_size,
                              hipStream_t stream)
{
    const int*   spin = (const int*)  d_in[0];
    const float* lr   = (const float*)d_in[1];
    const float* li   = (const float*)d_in[2];
    const float* br   = (const float*)d_in[3];
    const float* bi   = (const float*)d_in[4];
    const float* rr   = (const float*)d_in[5];
    const float* ri   = (const float*)d_in[6];
    float2* out = (float2*)d_out;

    const size_t WS_NEEDED = (size_t)62 * 16384;   // 992 KB
    if (ws_size >= WS_NEEDED) {
        unsigned* ws = (unsigned*)d_ws;
        mps_preconvert<<<dim3(62), dim3(256), 0, stream>>>(br, bi, ws);
        mps_mfma2_kernel<<<dim3(256), dim3(512), 0, stream>>>(spin, lr, li, rr, ri, ws, out);
    } else {
        mps_mfma_kernel_fb<<<dim3(256), dim3(256), 0, stream>>>(spin, lr, li, br, bi, rr, ri, out);
    }
}